// Round 5
// baseline (308.488 us; speedup 1.0000x reference)
//
#include <hip/hip_runtime.h>
#include <hip/hip_bf16.h>
#include <stdint.h>

// ============================================================================
// Attention: out = softmax(mask((X_q Wq + bq)(X_k Wk + bk)^T / 8)) (X_v Wv + bv)
// B=4 S=4096 H=1024 D=64, fp32 in/out.
//
// R5 lesson (R2/R3/R4 all ~80-90us, ~4-5 B/cyc/CU): global_load_lds sustains
// ~1 outstanding req/wave -> HBM-latency DMA serializes. Fix: plain VGPR
// loads (real ILP) x high occupancy; no LDS in hot loops.
//
//   setup : W^T -> bf16 [n][1024] plain, mask -> float bias {0,-1e30}
//   proj  : 768 x 256thr (12 waves/CU), 16x16x32 MFMA, 16-row strip/wave,
//           X + W^T fragments direct global->VGPR, ping-pong prefetch,
//           NO LDS/barriers in K-loop. Epilogue via 8KB LDS bounce.
//   flash : 512 x 256thr (2 blk/CU), q-tile 32, 4-way key split per block.
//           K/V/bias direct from global (L2-hot, 1MB/batch). 32x32x16 MFMA,
//           S^T=K*Q^T, p=exp2(s*scale+bias) one-pass (logits bounded),
//           PV A=V^T direct loads, P via shfl_xor(32) lane-pair exchange.
//           LDS only for 4-wave combine epilogue.
// ============================================================================

typedef __bf16 bf16;
typedef __bf16 bf16x8 __attribute__((ext_vector_type(8)));
typedef float f32x4 __attribute__((ext_vector_type(4)));
typedef float f32x16 __attribute__((ext_vector_type(16)));

union B8 { uint4 u; bf16x8 v; uint32_t w[4]; };

#define KSC 0.18033688011112042f  // 0.125 * log2(e)

// ---------------------------------------------------------------------------
// setup: items 0..24575   : W transpose+cast, one 16B wT chunk per thread
//        items 24576..28671: mask -> bias, 4 elements per thread (float4)
// wT layout: [mat][n][1024 k] bf16, plain row-major
// ---------------------------------------------------------------------------
__global__ void setup_kernel(const float* __restrict__ Wq, const float* __restrict__ Wk,
                             const float* __restrict__ Wv, const int* __restrict__ mask,
                             bf16* __restrict__ wT, float* __restrict__ biasArr)
{
  int item = blockIdx.x * 256 + threadIdx.x;
  if (item < 24576) {
    int mat = item >> 13;          // 8192 items per matrix
    int rem = item & 8191;
    int n   = rem >> 7;            // 0..63 (col of W)
    int c   = rem & 127;           // 16B chunk id along k
    const float* W = (mat == 0) ? Wq : (mat == 1) ? Wk : Wv;
    union { bf16 b[8]; uint4 u; } pk;
    #pragma unroll
    for (int j = 0; j < 8; ++j)
      pk.b[j] = (bf16)W[(c * 8 + j) * 64 + n];
    bf16* o = wT + mat * 65536;
    *(uint4*)(o + n * 1024 + c * 8) = pk.u;
  } else {
    int i = (item - 24576) << 2;
    const int4 m = *(const int4*)(mask + i);
    float4 b;
    b.x = m.x ? 0.0f : -1e30f;
    b.y = m.y ? 0.0f : -1e30f;
    b.z = m.z ? 0.0f : -1e30f;
    b.w = m.w ? 0.0f : -1e30f;
    *(float4*)(biasArr + i) = b;
  }
}

// ---------------------------------------------------------------------------
// proj: 768 blocks x 256 thr. Block = 64-row tile (4 waves x 16-row strips).
// 16x16x32 MFMA: A lane: m=lane&15, k=(lane>>4)*8+j; B lane: n=lane&15,
// k=(lane>>4)*8+j; C: row m=(lane>>4)*4+r, col n=lane&15.  [m89 layout]
// ---------------------------------------------------------------------------
__global__ __launch_bounds__(256, 3) void proj_kernel(
    const float* __restrict__ Xq, const float* __restrict__ Xk, const float* __restrict__ Xv,
    const bf16* __restrict__ wT,
    const float* __restrict__ bq, const float* __restrict__ bk, const float* __restrict__ bv,
    bf16* __restrict__ qo, bf16* __restrict__ ko, bf16* __restrict__ vTo)
{
  const int bx = blockIdx.x;
  const int mat = bx >> 8;            // 256 blocks per matrix
  const int m0 = (bx & 255) << 6;     // 64-row tile base
  const float* X    = (mat == 0) ? Xq : (mat == 1) ? Xk : Xv;
  const float* bias = (mat == 0) ? bq : (mat == 1) ? bk : bv;
  const bf16* w = wT + mat * 65536;

  __shared__ __align__(16) bf16 cs[64 * 64];   // 8 KB C bounce tile

  const int tid  = threadIdx.x;
  const int wv   = tid >> 6;
  const int lane = tid & 63;
  const int mrow = lane & 15;     // m (and n) lane index
  const int kg   = lane >> 4;     // k-group 0..3

  const float* xp = X + (size_t)(m0 + wv * 16 + mrow) * 1024 + kg * 8;
  const bf16* wp0 = w + (size_t)(mrow)      * 1024 + kg * 8;
  const bf16* wp1 = w + (size_t)(16 + mrow) * 1024 + kg * 8;
  const bf16* wp2 = w + (size_t)(32 + mrow) * 1024 + kg * 8;
  const bf16* wp3 = w + (size_t)(48 + mrow) * 1024 + kg * 8;

  f32x4 acc[4] = {};            // n-groups 0..3 (16 n each)

  // ping-pong register buffers: [buf][s] with s = k-step (32 k each)
  float4 xa[2][2], xb[2][2];
  uint4  wf[2][4][2];

  #define LOADC(buf, c)                                                     \
    {                                                                       \
      _Pragma("unroll")                                                     \
      for (int s = 0; s < 2; ++s) {                                         \
        xa[buf][s] = *(const float4*)(xp + (c) * 64 + s * 32);              \
        xb[buf][s] = *(const float4*)(xp + (c) * 64 + s * 32 + 4);          \
        wf[buf][0][s] = *(const uint4*)(wp0 + (c) * 64 + s * 32);           \
        wf[buf][1][s] = *(const uint4*)(wp1 + (c) * 64 + s * 32);           \
        wf[buf][2][s] = *(const uint4*)(wp2 + (c) * 64 + s * 32);           \
        wf[buf][3][s] = *(const uint4*)(wp3 + (c) * 64 + s * 32);           \
      }                                                                     \
    }

  LOADC(0, 0);
  #pragma unroll
  for (int c = 0; c < 16; ++c) {
    if (c < 15) LOADC((c + 1) & 1, c + 1);
    const int b = c & 1;
    #pragma unroll
    for (int s = 0; s < 2; ++s) {
      union { bf16 e[8]; bf16x8 v; } af;
      af.e[0] = (bf16)xa[b][s].x; af.e[1] = (bf16)xa[b][s].y;
      af.e[2] = (bf16)xa[b][s].z; af.e[3] = (bf16)xa[b][s].w;
      af.e[4] = (bf16)xb[b][s].x; af.e[5] = (bf16)xb[b][s].y;
      af.e[6] = (bf16)xb[b][s].z; af.e[7] = (bf16)xb[b][s].w;
      #pragma unroll
      for (int g = 0; g < 4; ++g) {
        B8 wb8; wb8.u = wf[b][g][s];
        acc[g] = __builtin_amdgcn_mfma_f32_16x16x32_bf16(af.v, wb8.v, acc[g], 0, 0, 0);
      }
    }
  }
  #undef LOADC

  // epilogue: bias add, stash [64 m][64 n] bf16 tile in LDS
  #pragma unroll
  for (int g = 0; g < 4; ++g) {
    float bv = bias[g * 16 + mrow];
    #pragma unroll
    for (int r = 0; r < 4; ++r) {
      int row = wv * 16 + kg * 4 + r;
      cs[row * 64 + g * 16 + mrow] = (bf16)(acc[g][r] + bv);
    }
  }
  __syncthreads();

  if (mat < 2) {
    // q/k: plain row-major [16384][64] bf16
    bf16* gout = (mat == 0) ? qo : ko;
    #pragma unroll
    for (int p = 0; p < 2; ++p) {
      int id = p * 256 + tid;
      int r = id >> 3;
      int c = id & 7;
      *(uint4*)(gout + (size_t)(m0 + r) * 64 + c * 8) = *(const uint4*)(cs + r * 64 + c * 8);
    }
  } else {
    // v: transposed plain [b][64 d][4096 s] bf16
    int batch = m0 >> 12;
    int tb = m0 & 4095;
    #pragma unroll
    for (int p = 0; p < 2; ++p) {
      int id = p * 256 + tid;
      int d  = id >> 3;
      int cc = id & 7;
      union { bf16 b[8]; uint4 u; } pk;
      #pragma unroll
      for (int j = 0; j < 8; ++j) pk.b[j] = cs[(cc * 8 + j) * 64 + d];
      *(uint4*)(vTo + ((size_t)batch * 64 + d) * 4096 + tb + cc * 8) = pk.u;
    }
  }
}

// ---------------------------------------------------------------------------
// flash: block = 32 queries, 4 waves, wave w owns keys [w*1024, +1024)
// in 16 tiles of 64. All operands direct from global (L2-hot). No barriers
// in main loop; 4-wave LDS combine at the end.
// ---------------------------------------------------------------------------
__global__ __launch_bounds__(256, 2) void flash_kernel(
    const bf16* __restrict__ qb, const bf16* __restrict__ kb, const bf16* __restrict__ vT,
    const float* __restrict__ biasArr, float* __restrict__ out)
{
  __shared__ __align__(16) float nb[4][32 * 68];
  __shared__ float dn[4][32];

  const int tid = threadIdx.x;
  const int lane = tid & 63;
  const int wv = tid >> 6;
  const int half = lane >> 5;
  const int ln = lane & 31;

  const int batch = blockIdx.x >> 7;
  const int q0 = (blockIdx.x & 127) << 5;

  // Q fragments (B-operand: n=q=lane&31, k=(lane>>5)*8 + s*16)
  bf16x8 qf[4];
  const bf16* qbase = qb + ((size_t)batch * 4096 + q0) * 64;
  #pragma unroll
  for (int s = 0; s < 4; ++s) {
    B8 t; t.u = *(const uint4*)(qbase + ln * 64 + (2 * s + half) * 8);
    qf[s] = t.v;
  }

  f32x16 acc[2] = {};           // [d-half], C: col=q, rows=d
  float den0 = 0.f;

  const bf16* kgb = kb + (size_t)batch * 4096 * 64;
  const bf16* vgb = vT + (size_t)batch * 64 * 4096;
  const float* barr = biasArr + batch * 4096;

  for (int it = 0; it < 16; ++it) {
    const int key0 = wv * 1024 + it * 64;
    #pragma unroll
    for (int st = 0; st < 2; ++st) {
      // S^T tile = K * Q^T : rows = 32 keys, cols = 32 queries
      f32x16 s0 = {};
      #pragma unroll
      for (int s = 0; s < 4; ++s) {
        B8 af; af.u = *(const uint4*)(kgb + (size_t)(key0 + st * 32 + ln) * 64 + (2 * s + half) * 8);
        s0 = __builtin_amdgcn_mfma_f32_32x32x16_bf16(af.v, qf[s], s0, 0, 0, 0);
      }
      // bias per C-row (key): reg r -> key (r&3)+8*(r>>2)+4*half (tile-local)
      float bb[16];
      #pragma unroll
      for (int g = 0; g < 4; ++g)
        *(float4*)&bb[4 * g] = *(const float4*)(barr + key0 + st * 32 + 8 * g + half * 4);
      // p = exp2(s*KSC + bias); accumulate denominator; pack bf16 pairs
      uint32_t pk0[8];
      #pragma unroll
      for (int i = 0; i < 8; ++i) {
        float a0 = __builtin_amdgcn_exp2f(fmaf(s0[2 * i],     KSC, bb[2 * i]));
        float a1 = __builtin_amdgcn_exp2f(fmaf(s0[2 * i + 1], KSC, bb[2 * i + 1]));
        den0 += a0 + a1;
        union { bf16 b[2]; uint32_t u; } u0;
        u0.b[0] = (bf16)a0; u0.b[1] = (bf16)a1;
        pk0[i] = u0.u;
      }
      // lane-pair exchange: C-layout P^T -> B-operand fragments
      uint32_t xp0[8];
      #pragma unroll
      for (int i = 0; i < 8; ++i)
        xp0[i] = (uint32_t)__shfl_xor((int)pk0[i], 32);
      #pragma unroll
      for (int t = 0; t < 2; ++t) {
        B8 p0f;
        p0f.w[0] = half ? xp0[4 * t + 2] : pk0[4 * t];
        p0f.w[1] = half ? xp0[4 * t + 3] : pk0[4 * t + 1];
        p0f.w[2] = half ? pk0[4 * t + 2] : xp0[4 * t];
        p0f.w[3] = half ? pk0[4 * t + 3] : xp0[4 * t + 1];
        #pragma unroll
        for (int dh = 0; dh < 2; ++dh) {
          B8 vf; vf.u = *(const uint4*)(vgb + (size_t)(dh * 32 + ln) * 4096 + key0 + (st * 4 + t * 2 + half) * 8);
          acc[dh] = __builtin_amdgcn_mfma_f32_32x32x16_bf16(vf.v, p0f.v, acc[dh], 0, 0, 0);
        }
      }
    }
  }

  // full denominator per query (each half-lane saw half the keys)
  den0 += __shfl_xor(den0, 32);

  // write partials: nb[wv][q][d]  (d = dh*32 + 8g + 4*half + (r&3))
  #pragma unroll
  for (int dh = 0; dh < 2; ++dh)
  #pragma unroll
  for (int g = 0; g < 4; ++g) {
    f32x16 a = acc[dh];
    *(float4*)(&nb[wv][ln * 68 + dh * 32 + 8 * g + half * 4]) =
        make_float4(a[4 * g], a[4 * g + 1], a[4 * g + 2], a[4 * g + 3]);
  }
  if (half == 0) dn[wv][ln] = den0;
  __syncthreads();

  // final: out[q][d] = sum_w nb[w][q][d] / sum_w dn[w][q]
  #pragma unroll
  for (int p = 0; p < 2; ++p) {
    int i = p * 1024 + tid * 4;
    int q = i >> 6;
    int d = i & 63;
    float4 v0 = *(const float4*)(&nb[0][q * 68 + d]);
    float4 v1 = *(const float4*)(&nb[1][q * 68 + d]);
    float4 v2 = *(const float4*)(&nb[2][q * 68 + d]);
    float4 v3 = *(const float4*)(&nb[3][q * 68 + d]);
    float dd = dn[0][q] + dn[1][q] + dn[2][q] + dn[3][q];
    float inv = 1.0f / dd;
    float4 o = make_float4((v0.x + v1.x + v2.x + v3.x) * inv,
                           (v0.y + v1.y + v2.y + v3.y) * inv,
                           (v0.z + v1.z + v2.z + v3.z) * inv,
                           (v0.w + v1.w + v2.w + v3.w) * inv);
    *(float4*)(out + ((size_t)batch * 4096 + q0 + q) * 64 + d) = o;
  }
}

// ---------------------------------------------------------------------------
extern "C" void kernel_launch(void* const* d_in, const int* in_sizes, int n_in,
                              void* d_out, int out_size, void* d_ws, size_t ws_size,
                              hipStream_t stream)
{
  const float* query = (const float*)d_in[0];
  const float* key   = (const float*)d_in[1];
  const float* value = (const float*)d_in[2];
  const int*   mask  = (const int*)d_in[3];
  const float* Wq    = (const float*)d_in[4];
  const float* bq    = (const float*)d_in[5];
  const float* Wk    = (const float*)d_in[6];
  const float* bk    = (const float*)d_in[7];
  const float* Wv    = (const float*)d_in[8];
  const float* bv    = (const float*)d_in[9];
  float* out = (float*)d_out;

  // workspace carve (bf16 elems): q 1M, k 1M, vT 1M, wT 192K, bias 16K floats
  bf16* qb = (bf16*)d_ws;
  bf16* kb = qb + 1048576;
  bf16* vT = kb + 1048576;
  bf16* wT = vT + 1048576;                       // 3*64*1024
  float* biasArr = (float*)((char*)d_ws + 3 * 2097152 + 393216);

  setup_kernel<<<112, 256, 0, stream>>>(Wq, Wk, Wv, mask, wT, biasArr);
  proj_kernel<<<768, 256, 0, stream>>>(query, key, value, wT, bq, bk, bv, qb, kb, vT);
  flash_kernel<<<512, 256, 0, stream>>>(qb, kb, vT, biasArr, out);
}